// Round 10
// baseline (192.585 us; speedup 1.0000x reference)
//
#include <hip/hip_runtime.h>
#include <math.h>

#define B_ 256
#define N_ 128
#define D_ 128
#define L_ 32
#define E_ 262144
#define PW_ 254          // bitmap words per graph = 8128/32
#define DCAP 96          // per-node neighbor capacity (max deg ~40 expected)

// workspace layout (u32 units)
#define NDEG_OFF 0               // 32768 u32 per-node degree counters
#define BM_OFF   32768           // 65024 u32 pair-target bitmap
#define KLS_OFF  97792           // 256 f32 per-graph KL sums
#define LP_OFF   98048           // 256 f32 per-graph log_prob sums
#define CNT_OFF  98304           // 1 u32 decoder arrival counter (pad to 98320)
#define ADJ_OFF  98320           // 32768*96 u8 CSR neighbor lists (786432 u32)
#define Z_OFF    884752          // 32768*32 f32 latents
#define ZERO_WORDS 98320         // ndeg + bitmap + kls + logp + cnt

// ---------------------------------------------------------------------------
// Per-edge: CSR adjacency build (atomics over 32768 node counters) + bitmap.
__global__ __launch_bounds__(256) void k_build(
    const int* __restrict__ ei, unsigned* __restrict__ ndeg,
    unsigned char* __restrict__ adj, unsigned* __restrict__ bm)
{
    int e = blockIdx.x * 256 + threadIdx.x;
    int src = ei[e], dst = ei[E_ + e];
    unsigned s1 = atomicAdd(&ndeg[src], 1u);
    if (s1 < DCAP) adj[(size_t)src * DCAP + s1] = (unsigned char)(dst & 127);
    unsigned s2 = atomicAdd(&ndeg[dst], 1u);
    if (s2 < DCAP) adj[(size_t)dst * DCAP + s2] = (unsigned char)(src & 127);
    int li = src & 127, lj = dst & 127, g = src >> 7;
    int p = li * (255 - li) / 2 + (lj - li - 1);
    atomicOr(&bm[g * PW_ + (p >> 5)], 1u << (p & 31));
}

// ---------------------------------------------------------------------------
// Fused encoder: block = 32 rows (quarter graph), 1024 blocks, XCD-swizzled
// (graph = blockIdx&255; 256≡0 mod 8 keeps a graph on one XCD).
// The neighbor aggregation is computed as a DENSE GEMM instead of a
// latency-bound gather: build Ã-quarter (I+A, 32x128, multiplicity-
// preserving) in LDS via ~512 LDS atomics from the CSR, then
// XA = Ã @ X_graph with the same 4x4 micro-tile loop as GEMM1 (X staged in
// 32-row chunks). Then h = relu(XA@W1+b1), [mu|ls] = h@WB, z/KL epilogue.
// ~33 KB LDS -> 4 blocks/CU. No register-held prefetch (round-8 spill).
__global__ __launch_bounds__(256, 4) void k_encoder(
    const float* __restrict__ x, const unsigned* __restrict__ ndeg,
    const unsigned char* __restrict__ adj,
    const float* __restrict__ W1, const float* __restrict__ b1,
    const float* __restrict__ Wmu, const float* __restrict__ bmu,
    const float* __restrict__ Wls, const float* __restrict__ bls,
    const float* __restrict__ eps,
    float* __restrict__ z, float* __restrict__ kls)
{
    __shared__ float As[32 * 132];    // Ã-quarter -> XA -> H (stride 132)
    __shared__ float Ws[4096];        // X chunk / W1 quarter / WB half
    int t = threadIdx.x;
    int g = blockIdx.x & 255;         // graph (fixes XCD: g % 8)
    int quar = blockIdx.x >> 8;       // 0..3
    int row0 = g * 128 + quar * 32;
    int rg = t >> 5;                  // 0..7
    int cg = t & 31;                  // 0..31
    int lane = t & 63;

    // ---- phase A: build Ã-quarter in LDS ----
    {
        float4 z4 = make_float4(0.f, 0.f, 0.f, 0.f);
        for (int c = t; c < 1056; c += 256) ((float4*)As)[c] = z4;
    }
    __syncthreads();
    {
        int nd = t >> 3, sub = t & 7; // 32 nodes x 8 threads
        int gnode = row0 + nd;
        int deg = (int)ndeg[gnode];
        if (deg > DCAP) deg = DCAP;
        const unsigned char* al = adj + (size_t)gnode * DCAP;
        if (sub == 0) As[nd * 132 + quar * 32 + nd] = 1.0f;   // I term
        for (int e = sub; e < deg; e += 8)
            atomicAdd(&As[nd * 132 + (int)al[e]], 1.0f);
    }
    __syncthreads();

    // ---- phase AG: XA = Ã @ X_graph, X staged in 4 chunks of 32 rows ----
    float acc[4][4];
    #pragma unroll
    for (int i = 0; i < 4; ++i)
        #pragma unroll
        for (int j = 0; j < 4; ++j) acc[i][j] = 0.f;

    for (int kc = 0; kc < 4; ++kc) {
        if (kc) __syncthreads();
        const float* xg = x + ((size_t)(g * 128 + kc * 32)) * 128;
        #pragma unroll
        for (int i = 0; i < 4; ++i) {
            int c = t + i * 256;      // 1024 float4 = 32 rows x 128 cols
            ((float4*)Ws)[c] = ((const float4*)xg)[c];
        }
        __syncthreads();
        #pragma unroll 2
        for (int k = 0; k < 32; k += 4) {
            float4 av[4], wv[4];
            #pragma unroll
            for (int i = 0; i < 4; ++i)
                av[i] = *(const float4*)(As + (4 * rg + i) * 132 + kc * 32 + k);
            #pragma unroll
            for (int dk = 0; dk < 4; ++dk)
                wv[dk] = *(const float4*)(Ws + (k + dk) * 128 + 4 * cg);
            #pragma unroll
            for (int i = 0; i < 4; ++i) {
                acc[i][0] += av[i].x * wv[0].x + av[i].y * wv[1].x + av[i].z * wv[2].x + av[i].w * wv[3].x;
                acc[i][1] += av[i].x * wv[0].y + av[i].y * wv[1].y + av[i].z * wv[2].y + av[i].w * wv[3].y;
                acc[i][2] += av[i].x * wv[0].z + av[i].y * wv[1].z + av[i].z * wv[2].z + av[i].w * wv[3].z;
                acc[i][3] += av[i].x * wv[0].w + av[i].y * wv[1].w + av[i].z * wv[2].w + av[i].w * wv[3].w;
            }
        }
    }
    __syncthreads();                  // all Ã reads done -> overwrite with XA
    #pragma unroll
    for (int i = 0; i < 4; ++i)
        *(float4*)(As + (4 * rg + i) * 132 + 4 * cg) =
            make_float4(acc[i][0], acc[i][1], acc[i][2], acc[i][3]);

    // ---- phase 1: h = relu(XA @ W1 + b1), W1 in 4 K-quarters ----
    #pragma unroll
    for (int i = 0; i < 4; ++i)
        #pragma unroll
        for (int j = 0; j < 4; ++j) acc[i][j] = 0.f;

    for (int kq = 0; kq < 4; ++kq) {
        __syncthreads();              // XA visible (kq=0) / prior Ws reads done
        #pragma unroll
        for (int i = 0; i < 4; ++i) {
            int c = t + i * 256;      // 1024 float4 = 32x128 W1 rows
            ((float4*)Ws)[c] = ((const float4*)(W1 + kq * 4096))[c];
        }
        __syncthreads();
        #pragma unroll 2
        for (int k = 0; k < 32; k += 4) {
            float4 av[4], wv[4];
            #pragma unroll
            for (int i = 0; i < 4; ++i)
                av[i] = *(const float4*)(As + (4 * rg + i) * 132 + kq * 32 + k);
            #pragma unroll
            for (int dk = 0; dk < 4; ++dk)
                wv[dk] = *(const float4*)(Ws + (k + dk) * 128 + 4 * cg);
            #pragma unroll
            for (int i = 0; i < 4; ++i) {
                acc[i][0] += av[i].x * wv[0].x + av[i].y * wv[1].x + av[i].z * wv[2].x + av[i].w * wv[3].x;
                acc[i][1] += av[i].x * wv[0].y + av[i].y * wv[1].y + av[i].z * wv[2].y + av[i].w * wv[3].y;
                acc[i][2] += av[i].x * wv[0].z + av[i].y * wv[1].z + av[i].z * wv[2].z + av[i].w * wv[3].z;
                acc[i][3] += av[i].x * wv[0].w + av[i].y * wv[1].w + av[i].z * wv[2].w + av[i].w * wv[3].w;
            }
        }
    }
    __syncthreads();                  // all XA reads done -> reuse as HS

    {
        float4 bb = *(const float4*)(b1 + 4 * cg);
        #pragma unroll
        for (int i = 0; i < 4; ++i) {
            float4 h;
            h.x = fmaxf(acc[i][0] + bb.x, 0.f);
            h.y = fmaxf(acc[i][1] + bb.y, 0.f);
            h.z = fmaxf(acc[i][2] + bb.z, 0.f);
            h.w = fmaxf(acc[i][3] + bb.w, 0.f);
            *(float4*)(As + (4 * rg + i) * 132 + 4 * cg) = h;
        }
    }

    // ---- phase 2: [mu|ls] = h @ WB + bias, WB in 2 K-halves ----
    float a3[4][2];
    #pragma unroll
    for (int i = 0; i < 4; ++i) { a3[i][0] = 0.f; a3[i][1] = 0.f; }

    for (int kh = 0; kh < 2; ++kh) {
        __syncthreads();              // HS visible (kh=0) / prior Ws reads done
        #pragma unroll
        for (int i = 0; i < 4; ++i) {
            int c = t + i * 256;      // 1024 float4 = 64 rows x 64 cols
            int row = c >> 4, col4 = (c & 15) << 2;
            int rowg = kh * 64 + row;
            float4 v = (col4 < 32) ? *(const float4*)(Wmu + rowg * 32 + col4)
                                   : *(const float4*)(Wls + rowg * 32 + col4 - 32);
            *(float4*)(Ws + row * 64 + col4) = v;
        }
        __syncthreads();
        #pragma unroll 2
        for (int k = 0; k < 64; k += 4) {
            float4 av[4];
            float2 wv[4];
            #pragma unroll
            for (int i = 0; i < 4; ++i)
                av[i] = *(const float4*)(As + (4 * rg + i) * 132 + kh * 64 + k);
            #pragma unroll
            for (int dk = 0; dk < 4; ++dk)
                wv[dk] = *(const float2*)(Ws + (k + dk) * 64 + 2 * cg);
            #pragma unroll
            for (int i = 0; i < 4; ++i) {
                a3[i][0] += av[i].x * wv[0].x + av[i].y * wv[1].x + av[i].z * wv[2].x + av[i].w * wv[3].x;
                a3[i][1] += av[i].x * wv[0].y + av[i].y * wv[1].y + av[i].z * wv[2].y + av[i].w * wv[3].y;
            }
        }
    }
    {
        float2 bv = (cg < 16) ? *(const float2*)(bmu + 2 * cg)
                              : *(const float2*)(bls + 2 * cg - 32);
        #pragma unroll
        for (int i = 0; i < 4; ++i) { a3[i][0] += bv.x; a3[i][1] += bv.y; }
    }

    // exchange mu<->ls with partner lane (cg ^ 16)
    float o3[4][2];
    #pragma unroll
    for (int i = 0; i < 4; ++i) {
        o3[i][0] = __shfl_xor(a3[i][0], 16);
        o3[i][1] = __shfl_xor(a3[i][1], 16);
    }

    // ---- phase 3: z = mu + exp(ls)*eps, KL; wave shfl-reduce, 1 atomic ----
    float klsum = 0.f;
    if (cg < 16) {                    // this lane holds mu; partner held ls
        int lo = cg;
        #pragma unroll
        for (int i = 0; i < 4; ++i) {
            int rowg = row0 + 4 * rg + i;
            float mu0 = a3[i][0], mu1 = a3[i][1];
            float ls0 = o3[i][0], ls1 = o3[i][1];
            float2 ev = *(const float2*)(eps + (size_t)rowg * 32 + 2 * lo);
            float s0 = __expf(ls0), s1 = __expf(ls1);
            float2 zv = make_float2(mu0 + s0 * ev.x, mu1 + s1 * ev.y);
            *(float2*)(z + (size_t)rowg * 32 + 2 * lo) = zv;
            klsum += s0 * s0 + mu0 * mu0 - 1.f - 2.f * ls0
                   + s1 * s1 + mu1 * mu1 - 1.f - 2.f * ls1;
        }
    }
    #pragma unroll
    for (int off = 32; off > 0; off >>= 1) klsum += __shfl_xor(klsum, off);
    if (lane == 0) atomicAdd(&kls[g], 0.5f * klsum);
}

// ---------------------------------------------------------------------------
// Decoder: 4 blocks per graph (i-quarters), XCD-swizzled; shfl-reduce +
// one atomic per wave. Fused finalize: last-arriving block (device-scope
// counter) reduces logp-kls over all graphs and writes out[0]. logp is read
// back with atomic-fetch (cross-XCD coherence); kls crosses a kernel
// boundary (safe for plain loads).
__global__ __launch_bounds__(256) void k_decoder(
    const float* __restrict__ z, const unsigned* __restrict__ bitmap,
    const float* __restrict__ kls, float* __restrict__ logp,
    unsigned* __restrict__ cnt, float* __restrict__ out)
{
    __shared__ float zT[32 * 132];
    __shared__ unsigned bm[PW_];
    __shared__ unsigned sOld;
    int b = blockIdx.x & 255, quar = blockIdx.x >> 8, t = threadIdx.x;

    #pragma unroll
    for (int i = 0; i < 16; ++i) {
        int c = t + i * 256;
        int n = c >> 5, l = c & 31;
        zT[l * 132 + n] = z[((size_t)b * N_ + n) * L_ + l];
    }
    if (t < PW_) bm[t] = bitmap[b * PW_ + t];
    __syncthreads();

    int i0 = quar * 32 + ((t >> 5) << 2);
    int j0 = (t & 31) << 2;
    float g[4][4];
    #pragma unroll
    for (int a = 0; a < 4; ++a)
        #pragma unroll
        for (int c = 0; c < 4; ++c) g[a][c] = 0.f;

    #pragma unroll 4
    for (int l = 0; l < 32; ++l) {
        float4 a0 = *(const float4*)(zT + l * 132 + i0);
        float4 b0 = *(const float4*)(zT + l * 132 + j0);
        float za[4] = {a0.x, a0.y, a0.z, a0.w};
        float zb[4] = {b0.x, b0.y, b0.z, b0.w};
        #pragma unroll
        for (int a = 0; a < 4; ++a)
            #pragma unroll
            for (int c = 0; c < 4; ++c) g[a][c] += za[a] * zb[c];
    }

    float sum = 0.f;
    #pragma unroll
    for (int a = 0; a < 4; ++a) {
        int i = i0 + a;
        #pragma unroll
        for (int c = 0; c < 4; ++c) {
            int j = j0 + c;
            if (j > i) {
                float lg = g[a][c];
                int p = i * (255 - i) / 2 + (j - i - 1);
                unsigned bit = (bm[p >> 5] >> (p & 31)) & 1u;
                float sp = __logf(1.f + __expf(-fabsf(lg))) + fmaxf(lg, 0.f);
                sum += bit ? (lg - sp) : (-sp);
            }
        }
    }
    #pragma unroll
    for (int off = 32; off > 0; off >>= 1) sum += __shfl_xor(sum, off);
    if ((t & 63) == 0) atomicAdd(&logp[b], sum);

    // ---- fused finalize ----
    __syncthreads();                  // barrier drains the waves' atomics
    if (t == 0) { __threadfence(); sOld = atomicAdd(cnt, 1u); }
    __syncthreads();
    if (sOld == 4 * B_ - 1) {
        __threadfence();
        float lp = atomicAdd(&logp[t], 0.0f);   // coherent read-back
        float kv = kls[t];
        float* RED = zT;              // reuse (all zT reads done)
        RED[t] = lp - kv;
        __syncthreads();
        for (int s = 128; s > 0; s >>= 1) {
            if (t < s) RED[t] += RED[t + s];
            __syncthreads();
        }
        if (t == 0) out[0] = -RED[0] * (1.0f / 256.0f);
    }
}

// ---------------------------------------------------------------------------
extern "C" void kernel_launch(void* const* d_in, const int* in_sizes, int n_in,
                              void* d_out, int out_size, void* d_ws, size_t ws_size,
                              hipStream_t stream) {
    const float* x   = (const float*)d_in[0];
    const int*   ei  = (const int*)d_in[1];
    // d_in[2] = batch (unused; block-contiguous layout known)
    const float* eps = (const float*)d_in[3];
    const float* W1  = (const float*)d_in[4];
    const float* b1  = (const float*)d_in[5];
    const float* Wmu = (const float*)d_in[6];
    const float* bmu = (const float*)d_in[7];
    const float* Wls = (const float*)d_in[8];
    const float* bls = (const float*)d_in[9];

    unsigned* wsw = (unsigned*)d_ws;
    unsigned*      ndeg = wsw + NDEG_OFF;
    unsigned*      bm   = wsw + BM_OFF;
    float*         kls  = (float*)(wsw + KLS_OFF);
    float*         logp = (float*)(wsw + LP_OFF);
    unsigned*      cnt  = wsw + CNT_OFF;
    unsigned char* adj  = (unsigned char*)(wsw + ADJ_OFF);
    float*         z    = (float*)(wsw + Z_OFF);

    hipMemsetAsync(d_ws, 0, ZERO_WORDS * sizeof(unsigned), stream);

    k_build   <<<E_ / 256, 256, 0, stream>>>(ei, ndeg, adj, bm);
    k_encoder <<<1024, 256, 0, stream>>>(x, ndeg, adj, W1, b1, Wmu, bmu,
                                         Wls, bls, eps, z, kls);
    k_decoder <<<4 * B_, 256, 0, stream>>>(z, bm, kls, logp, cnt, (float*)d_out);
}